// Round 17
// baseline (75.870 us; speedup 1.0000x reference)
//
#include <hip/hip_runtime.h>
#include <math.h>

#define NTOK 16384
#define D_   2048
#define E_   64
#define TPB  64            // tokens per block (8 waves x 8 tokens)
#define NKC  (D_/32)       // 64 k32-steps

typedef _Float16 f16x8 __attribute__((ext_vector_type(8)));
typedef float    f32x4 __attribute__((ext_vector_type(4)));

#define LSCALE      256.0f          // pre-scale x and W before f16 split (denorm guard)
#define LSCALE2_INV (1.0f/65536.0f) // exact pow2 un-scale of acc

// ---- Kernel 1: W (E x D fp32) -> fragment-ordered f16 hi/lo, scaled x256 ----
// Fragment order: element j of lane l for (n-tile nt, k32-step kc) is
//   W[e = nt*16 + (l&15)][k = kc*32 + (l>>4)*4 + (j&3) + (j>=4 ? 16 : 0)]
// Same k-map as the A operand -> any deviation from HW k-order cancels.
__global__ __launch_bounds__(256)
void prep_w(const float* __restrict__ W,
            _Float16* __restrict__ wh, _Float16* __restrict__ wl)
{
    const int idx = blockIdx.x * 256 + threadIdx.x;   // 0..16383
    const int l  = idx & 63;
    const int kc = (idx >> 6) & 63;
    const int nt = idx >> 12;                          // 0..3
    const int e  = nt * 16 + (l & 15);
    const int g  = l >> 4;
    const float* src = W + (size_t)e * D_ + kc * 32 + g * 4;
    const float4 f0 = *reinterpret_cast<const float4*>(src);
    const float4 f1 = *reinterpret_cast<const float4*>(src + 16);
    const float v[8] = {f0.x, f0.y, f0.z, f0.w, f1.x, f1.y, f1.z, f1.w};
    f16x8 h, lo;
#pragma unroll
    for (int j = 0; j < 8; ++j) {
        const float vs = v[j] * LSCALE;
        const _Float16 hj = (_Float16)vs;
        h[j]  = hj;
        lo[j] = (_Float16)(vs - (float)hj);
    }
    *reinterpret_cast<f16x8*>(wh + (size_t)idx * 8) = h;
    *reinterpret_cast<f16x8*>(wl + (size_t)idx * 8) = lo;
}

// ---- Kernel 2: MFMA router -- fenced ILP x TLP ----
// 256 blocks x 512 threads (8 waves, 2 waves/SIMD). Wave w owns tokens
// T0+8w..+8w+7 in MFMA rows 0-7 (rows 8-15 duplicate rows 0-7 -- r13-proven
// bitwise-safe), ALL 64 experts (4 acc tiles). Zero barriers / zero LDS in
// the K-loop. Depth-4 register ring for x and B, PINNED with
// sched_barrier(0) after each prefetch group (r15's fence: the only thing
// that ever stopped hipcc from collapsing the ring; r15 held 132 VGPR and
// was the best round at 1 wave/SIMD -- this runs the same code at 2/SIMD).
// B L2-traffic: 8 waves/block share the same B stream through L1 -> 512 KB
// per block = 128 MB total (r16's minimum), without r16's barrier convoys.
// Per-(token,expert) chain (hh,lh,hl; kc ascending; same cvt, same fragment
// maps) is bitwise-identical to rounds 5-16 (absmax 1.0; do NOT reorder).
__global__ __launch_bounds__(512, 2)
void router_mfma(const float* __restrict__ x,
                 const _Float16* __restrict__ wh,
                 const _Float16* __restrict__ wl,
                 const float* __restrict__ bias,
                 float* __restrict__ out)
{
    __shared__ float smem[TPB * 65 + TPB * 4];   // logits [64][65] + res [64][4]

    const int tid = threadIdx.x;
    const int l   = tid & 63;
    const int w   = __builtin_amdgcn_readfirstlane(tid >> 6);  // 0..7
    const int T0  = blockIdx.x * TPB;
    const int g   = l >> 4;

    // row (l&15) -> token (l&7): rows 8-15 duplicate rows 0-7
    const float* xp = x + (size_t)(T0 + w * 8 + (l & 7)) * D_ + g * 4;
    const _Float16* bh_b = wh + (size_t)l * 8;   // + nt*32768 + kc*512
    const _Float16* bl_b = wl + (size_t)l * 8;

    f32x4 acc0 = {0.f,0.f,0.f,0.f}, acc1 = {0.f,0.f,0.f,0.f};
    f32x4 acc2 = {0.f,0.f,0.f,0.f}, acc3 = {0.f,0.f,0.f,0.f};

    float4 xa[4], xb[4];          // x ring, slot = kc&3 (static after unroll)
    f16x8  BH[4][4], BL[4][4];    // B ring, [slot][nt]

    // prologue: fill depth-4 ring (kc = 0..3)
#pragma unroll
    for (int j = 0; j < 4; ++j) {
        xa[j] = *reinterpret_cast<const float4*>(xp + j * 32);
        xb[j] = *reinterpret_cast<const float4*>(xp + j * 32 + 16);
#pragma unroll
        for (int nt = 0; nt < 4; ++nt) {
            BH[j][nt] = *reinterpret_cast<const f16x8*>(bh_b + nt * 32768 + j * 512);
            BL[j][nt] = *reinterpret_cast<const f16x8*>(bl_b + nt * 32768 + j * 512);
        }
    }

    // steady state: s = 0..14, unconditional prefetch, fence-pinned
    for (int s = 0; s < 15; ++s) {
        const int K = s << 2;
#pragma unroll
        for (int j = 0; j < 4; ++j) {
            // cvt (frozen math)
            f16x8 ah, al_;
            {
                float vs;
                vs = xa[j].x * LSCALE; ah[0] = (_Float16)vs; al_[0] = (_Float16)(vs - (float)ah[0]);
                vs = xa[j].y * LSCALE; ah[1] = (_Float16)vs; al_[1] = (_Float16)(vs - (float)ah[1]);
                vs = xa[j].z * LSCALE; ah[2] = (_Float16)vs; al_[2] = (_Float16)(vs - (float)ah[2]);
                vs = xa[j].w * LSCALE; ah[3] = (_Float16)vs; al_[3] = (_Float16)(vs - (float)ah[3]);
                vs = xb[j].x * LSCALE; ah[4] = (_Float16)vs; al_[4] = (_Float16)(vs - (float)ah[4]);
                vs = xb[j].y * LSCALE; ah[5] = (_Float16)vs; al_[5] = (_Float16)(vs - (float)ah[5]);
                vs = xb[j].z * LSCALE; ah[6] = (_Float16)vs; al_[6] = (_Float16)(vs - (float)ah[6]);
                vs = xb[j].w * LSCALE; ah[7] = (_Float16)vs; al_[7] = (_Float16)(vs - (float)ah[7]);
            }
            // 12 MFMA: per-tile chain hh, lh, hl (frozen)
            acc0 = __builtin_amdgcn_mfma_f32_16x16x32_f16(ah,  BH[j][0], acc0, 0, 0, 0);
            acc0 = __builtin_amdgcn_mfma_f32_16x16x32_f16(al_, BH[j][0], acc0, 0, 0, 0);
            acc0 = __builtin_amdgcn_mfma_f32_16x16x32_f16(ah,  BL[j][0], acc0, 0, 0, 0);
            acc1 = __builtin_amdgcn_mfma_f32_16x16x32_f16(ah,  BH[j][1], acc1, 0, 0, 0);
            acc1 = __builtin_amdgcn_mfma_f32_16x16x32_f16(al_, BH[j][1], acc1, 0, 0, 0);
            acc1 = __builtin_amdgcn_mfma_f32_16x16x32_f16(ah,  BL[j][1], acc1, 0, 0, 0);
            acc2 = __builtin_amdgcn_mfma_f32_16x16x32_f16(ah,  BH[j][2], acc2, 0, 0, 0);
            acc2 = __builtin_amdgcn_mfma_f32_16x16x32_f16(al_, BH[j][2], acc2, 0, 0, 0);
            acc2 = __builtin_amdgcn_mfma_f32_16x16x32_f16(ah,  BL[j][2], acc2, 0, 0, 0);
            acc3 = __builtin_amdgcn_mfma_f32_16x16x32_f16(ah,  BH[j][3], acc3, 0, 0, 0);
            acc3 = __builtin_amdgcn_mfma_f32_16x16x32_f16(al_, BH[j][3], acc3, 0, 0, 0);
            acc3 = __builtin_amdgcn_mfma_f32_16x16x32_f16(ah,  BL[j][3], acc3, 0, 0, 0);
            // prefetch kc+4 into the slot just consumed (depth-4 ring)
            {
                const int kn = K + j + 4;
                xa[j] = *reinterpret_cast<const float4*>(xp + kn * 32);
                xb[j] = *reinterpret_cast<const float4*>(xp + kn * 32 + 16);
#pragma unroll
                for (int nt = 0; nt < 4; ++nt) {
                    BH[j][nt] = *reinterpret_cast<const f16x8*>(bh_b + nt * 32768 + (size_t)kn * 512);
                    BL[j][nt] = *reinterpret_cast<const f16x8*>(bl_b + nt * 32768 + (size_t)kn * 512);
                }
            }
            // PIN: prefetches may not sink below this point.
            __builtin_amdgcn_sched_barrier(0);
        }
    }
    // peeled last superstep (kc 60..63): no prefetch, no fences
#pragma unroll
    for (int j = 0; j < 4; ++j) {
        f16x8 ah, al_;
        {
            float vs;
            vs = xa[j].x * LSCALE; ah[0] = (_Float16)vs; al_[0] = (_Float16)(vs - (float)ah[0]);
            vs = xa[j].y * LSCALE; ah[1] = (_Float16)vs; al_[1] = (_Float16)(vs - (float)ah[1]);
            vs = xa[j].z * LSCALE; ah[2] = (_Float16)vs; al_[2] = (_Float16)(vs - (float)ah[2]);
            vs = xa[j].w * LSCALE; ah[3] = (_Float16)vs; al_[3] = (_Float16)(vs - (float)ah[3]);
            vs = xb[j].x * LSCALE; ah[4] = (_Float16)vs; al_[4] = (_Float16)(vs - (float)ah[4]);
            vs = xb[j].y * LSCALE; ah[5] = (_Float16)vs; al_[5] = (_Float16)(vs - (float)ah[5]);
            vs = xb[j].z * LSCALE; ah[6] = (_Float16)vs; al_[6] = (_Float16)(vs - (float)ah[6]);
            vs = xb[j].w * LSCALE; ah[7] = (_Float16)vs; al_[7] = (_Float16)(vs - (float)ah[7]);
        }
        acc0 = __builtin_amdgcn_mfma_f32_16x16x32_f16(ah,  BH[j][0], acc0, 0, 0, 0);
        acc0 = __builtin_amdgcn_mfma_f32_16x16x32_f16(al_, BH[j][0], acc0, 0, 0, 0);
        acc0 = __builtin_amdgcn_mfma_f32_16x16x32_f16(ah,  BL[j][0], acc0, 0, 0, 0);
        acc1 = __builtin_amdgcn_mfma_f32_16x16x32_f16(ah,  BH[j][1], acc1, 0, 0, 0);
        acc1 = __builtin_amdgcn_mfma_f32_16x16x32_f16(al_, BH[j][1], acc1, 0, 0, 0);
        acc1 = __builtin_amdgcn_mfma_f32_16x16x32_f16(ah,  BL[j][1], acc1, 0, 0, 0);
        acc2 = __builtin_amdgcn_mfma_f32_16x16x32_f16(ah,  BH[j][2], acc2, 0, 0, 0);
        acc2 = __builtin_amdgcn_mfma_f32_16x16x32_f16(al_, BH[j][2], acc2, 0, 0, 0);
        acc2 = __builtin_amdgcn_mfma_f32_16x16x32_f16(ah,  BL[j][2], acc2, 0, 0, 0);
        acc3 = __builtin_amdgcn_mfma_f32_16x16x32_f16(ah,  BH[j][3], acc3, 0, 0, 0);
        acc3 = __builtin_amdgcn_mfma_f32_16x16x32_f16(al_, BH[j][3], acc3, 0, 0, 0);
        acc3 = __builtin_amdgcn_mfma_f32_16x16x32_f16(ah,  BL[j][3], acc3, 0, 0, 0);
    }

    // ---- C tiles -> LDS logits (rows 0-7 real; 8-15 duplicates skipped) ----
    // C layout: col = lane&15, row = (lane>>4)*4 + r; token = w*8 + row.
    if (g < 2) {
        const int col = l & 15;
#pragma unroll
        for (int r = 0; r < 4; ++r) {
            const int t = w * 8 + g * 4 + r;          // token 0..63
            smem[t * 65 + 0  + col] = acc0[r] * LSCALE2_INV;
            smem[t * 65 + 16 + col] = acc1[r] * LSCALE2_INV;
            smem[t * 65 + 32 + col] = acc2[r] * LSCALE2_INV;
            smem[t * 65 + 48 + col] = acc3[r] * LSCALE2_INV;
        }
    }
    __syncthreads();

    // ---- top-2 + 2-way softmax (frozen scan): thread t handles token t ----
    float* res = smem + TPB * 65;
    if (tid < TPB) {
        const float* lg = smem + tid * 65;
        float m1 = -INFINITY, m2 = -INFINITY;
        int i1 = 0, i2 = 0;
        for (int e = 0; e < E_; ++e) {
            const float v = lg[e] + bias[e];
            if (v > m1)      { m2 = m1; i2 = i1; m1 = v; i1 = e; }
            else if (v > m2) { m2 = v;  i2 = e; }
        }
        const float ex  = expf(m2 - m1);
        const float den = 1.f + ex;
        res[tid*4+0] = 1.f / den;
        res[tid*4+1] = ex / den;
        res[tid*4+2] = (float)i1;
        res[tid*4+3] = (float)i2;
    }
    __syncthreads();

    // ---- output: probs (64 tokens x 64 experts = 4096 floats), float4 ----
    float* ob = out + (size_t)T0 * E_;
#pragma unroll
    for (int i = 0; i < 2; ++i) {
        const int idx = i * 2048 + tid * 4;
        const int t   = idx >> 6;
        const int e0  = idx & 63;
        const float p1 = res[t*4+0];
        const float p2 = res[t*4+1];
        const int   i1 = (int)res[t*4+2];
        const int   i2 = (int)res[t*4+3];
        float4 v;
        v.x = (e0+0 == i1) ? p1 : ((e0+0 == i2) ? p2 : 0.f);
        v.y = (e0+1 == i1) ? p1 : ((e0+1 == i2) ? p2 : 0.f);
        v.z = (e0+2 == i1) ? p1 : ((e0+2 == i2) ? p2 : 0.f);
        v.w = (e0+3 == i1) ? p1 : ((e0+3 == i2) ? p2 : 0.f);
        *reinterpret_cast<float4*>(ob + idx) = v;
    }
    // ids as float values (whole d_out is read as float32)
    if (tid < TPB * 2) {
        out[(size_t)NTOK * E_ + (size_t)T0 * 2 + tid] =
            res[(tid >> 1) * 4 + 2 + (tid & 1)];
    }
}

extern "C" void kernel_launch(void* const* d_in, const int* in_sizes, int n_in,
                              void* d_out, int out_size, void* d_ws, size_t ws_size,
                              hipStream_t stream) {
    const float* x = (const float*)d_in[0];
    const float* W = (const float*)d_in[1];
    const float* b = (const float*)d_in[2];
    float* out     = (float*)d_out;
    _Float16* wh   = (_Float16*)d_ws;                       // 256 KB
    _Float16* wl   = wh + (size_t)4 * NKC * 64 * 8;         // +256 KB

    hipLaunchKernelGGL(prep_w, dim3(64), dim3(256), 0, stream, W, wh, wl);
    hipLaunchKernelGGL(router_mfma, dim3(NTOK / TPB), dim3(512), 0, stream,
                       x, wh, wl, b, out);
}

// Round 18
// 61.762 us; speedup vs baseline: 1.2284x; 1.2284x over previous
//
#include <hip/hip_runtime.h>
#include <math.h>

#define NTOK 16384
#define D_   2048
#define E_   64
#define TPB  64            // tokens per block (4 waves x 16 tokens)
#define NKC  (D_/32)       // 64 k32-steps

typedef _Float16 f16x8 __attribute__((ext_vector_type(8)));
typedef float    f32x4 __attribute__((ext_vector_type(4)));

#define LSCALE      256.0f          // pre-scale x and W before f16 split (denorm guard)
#define LSCALE2_INV (1.0f/65536.0f) // exact pow2 un-scale of acc

// LDS: per-wave PRIVATE depth-3 ring, page = 10240 B:
//   x  2048 B  ([16 rows][8 slots x 16B], slot XOR-swizzled by row&7)
//   B  8192 B  at +2048: [4 nt][hi 1KB | lo 1KB]
// Wave region 30720 B; block total 4 x 30720 = 122880 B.
// NO barriers in the K-loop: each wave stages only its own region and waits
// on its own (per-wave) vmcnt -> no convoys (r16's flaw), and the pipeline
// lives in LDS so hipcc cannot collapse it (r12-r17's flaw: every VGPR ring
// collapsed, VGPR 52..132 vs ~190 needed -> serialized ~1900 cyc/kc).
// Epilogue logits [64][65] + res alias wave 0's ring after a __syncthreads.
#define PAGE_B      10240
#define DEPTH       3
#define WAVE_B      (DEPTH * PAGE_B)        // 30720
#define SMEM_FLOATS (4 * WAVE_B / 4)        // 30720 floats = 122880 B

// ---- Kernel 1: W (E x D fp32) -> fragment-ordered f16 hi/lo, scaled x256 ----
// Fragment order: element j of lane l for (n-tile nt, k32-step kc) is
//   W[e = nt*16 + (l&15)][k = kc*32 + (l>>4)*4 + (j&3) + (j>=4 ? 16 : 0)]
// Same k-map as the A operand -> any deviation from HW k-order cancels.
__global__ __launch_bounds__(256)
void prep_w(const float* __restrict__ W,
            _Float16* __restrict__ wh, _Float16* __restrict__ wl)
{
    const int idx = blockIdx.x * 256 + threadIdx.x;   // 0..16383
    const int l  = idx & 63;
    const int kc = (idx >> 6) & 63;
    const int nt = idx >> 12;                          // 0..3
    const int e  = nt * 16 + (l & 15);
    const int g  = l >> 4;
    const float* src = W + (size_t)e * D_ + kc * 32 + g * 4;
    const float4 f0 = *reinterpret_cast<const float4*>(src);
    const float4 f1 = *reinterpret_cast<const float4*>(src + 16);
    const float v[8] = {f0.x, f0.y, f0.z, f0.w, f1.x, f1.y, f1.z, f1.w};
    f16x8 h, lo;
#pragma unroll
    for (int j = 0; j < 8; ++j) {
        const float vs = v[j] * LSCALE;
        const _Float16 hj = (_Float16)vs;
        h[j]  = hj;
        lo[j] = (_Float16)(vs - (float)hj);
    }
    *reinterpret_cast<f16x8*>(wh + (size_t)idx * 8) = h;
    *reinterpret_cast<f16x8*>(wl + (size_t)idx * 8) = lo;
}

__device__ __forceinline__ void stage16(const void* g, void* l) {
    __builtin_amdgcn_global_load_lds(
        (const __attribute__((address_space(1))) void*)g,
        (__attribute__((address_space(3))) void*)l, 16, 0, 0);
}

// ---- Kernel 2: MFMA router -- per-wave-private LDS pipeline, no barriers ----
// 256 blocks x 256 threads (4 waves, 64 tokens, 1 block/CU by LDS).
// Wave w = tokens T0+16w..+16w+15, ALL 64 experts (4 acc tiles).
// Per kc: wait own vmcnt(10) [page kc landed; kc+1 in flight] ->
// STAGE(kc+2) into the slot consumed at kc-1 (10 x 16B global_load_lds) ->
// COMPUTE page kc (10 ds_read, cvt, 12 MFMA). Loop unrolled x3 for static
// ring slots; peeled kc=63 waits vmcnt(0). Tail-safe by construction.
// Per-(token,expert) chain (hh,lh,hl; nt 0..3; kc ascending; same cvt, same
// fragment maps, same XOR swizzle) is bitwise-identical to rounds 5-17
// (absmax 1.0; do NOT reorder).
__global__ __launch_bounds__(256, 1)
void router_mfma(const float* __restrict__ x,
                 const _Float16* __restrict__ wh,
                 const _Float16* __restrict__ wl,
                 const float* __restrict__ bias,
                 float* __restrict__ out)
{
    __shared__ float smem[SMEM_FLOATS];
    char* sb = (char*)smem;

    const int tid = threadIdx.x;
    const int l   = tid & 63;
    const int w   = __builtin_amdgcn_readfirstlane(tid >> 6);  // 0..3
    const int T0  = blockIdx.x * TPB;
    const int g   = l >> 4;
    char* wb = sb + w * WAVE_B;          // this wave's private ring

    f32x4 acc0 = {0.f,0.f,0.f,0.f}, acc1 = {0.f,0.f,0.f,0.f};
    f32x4 acc2 = {0.f,0.f,0.f,0.f}, acc3 = {0.f,0.f,0.f,0.f};

    // --- staging sources: x instr A rows 0-7, instr B rows 8-15 of the
    // wave's 16 tokens; lane l -> row l>>3, linear slot l&7 holds source
    // slot (l&7)^(row&7)  (row&7 == l>>3 for both instrs).
    const int rlo = l >> 3;                           // 0..7
    const int ssl = (l & 7) ^ rlo;
    const float* xsA = x + (size_t)(T0 + w * 16 + rlo) * D_ + ssl * 4;
    const float* xsB = xsA + (size_t)8 * D_;
    const _Float16* bh_b = wh + (size_t)l * 8;        // + nt*32768 + kc*512
    const _Float16* bl_b = wl + (size_t)l * 8;

    auto STAGE = [&](int kc, int slot) {              // 10 x 16B, own region
        char* pg = wb + slot * PAGE_B;
        stage16(xsA + (size_t)kc * 32, pg);           // rows 0-7  (+lane*16)
        stage16(xsB + (size_t)kc * 32, pg + 1024);    // rows 8-15
#pragma unroll
        for (int nt = 0; nt < 4; ++nt) {
            stage16(bh_b + nt * 32768 + (size_t)kc * 512, pg + 2048 + nt * 2048);
            stage16(bl_b + nt * 32768 + (size_t)kc * 512, pg + 2048 + nt * 2048 + 1024);
        }
    };

    // --- compute-side LDS offsets (wave-local token row; match swizzle) ---
    const int trow   = l & 15;
    const int t7     = trow & 7;
    const int xa_off = trow * 128 + ((g       ^ t7) << 4);
    const int xb_off = trow * 128 + (((4 + g) ^ t7) << 4);

    auto COMPUTE = [&](int slot) {
        const char* pg = wb + slot * PAGE_B;
        const float4 xa = *reinterpret_cast<const float4*>(pg + xa_off);
        const float4 xb = *reinterpret_cast<const float4*>(pg + xb_off);
        const f16x8 bh0 = *reinterpret_cast<const f16x8*>(pg + 2048 + 0*2048 +        (l << 4));
        const f16x8 bl0 = *reinterpret_cast<const f16x8*>(pg + 2048 + 0*2048 + 1024 + (l << 4));
        const f16x8 bh1 = *reinterpret_cast<const f16x8*>(pg + 2048 + 1*2048 +        (l << 4));
        const f16x8 bl1 = *reinterpret_cast<const f16x8*>(pg + 2048 + 1*2048 + 1024 + (l << 4));
        const f16x8 bh2 = *reinterpret_cast<const f16x8*>(pg + 2048 + 2*2048 +        (l << 4));
        const f16x8 bl2 = *reinterpret_cast<const f16x8*>(pg + 2048 + 2*2048 + 1024 + (l << 4));
        const f16x8 bh3 = *reinterpret_cast<const f16x8*>(pg + 2048 + 3*2048 +        (l << 4));
        const f16x8 bl3 = *reinterpret_cast<const f16x8*>(pg + 2048 + 3*2048 + 1024 + (l << 4));
        f16x8 ah, al_;
        {
            float vs;
            vs = xa.x * LSCALE; ah[0] = (_Float16)vs; al_[0] = (_Float16)(vs - (float)ah[0]);
            vs = xa.y * LSCALE; ah[1] = (_Float16)vs; al_[1] = (_Float16)(vs - (float)ah[1]);
            vs = xa.z * LSCALE; ah[2] = (_Float16)vs; al_[2] = (_Float16)(vs - (float)ah[2]);
            vs = xa.w * LSCALE; ah[3] = (_Float16)vs; al_[3] = (_Float16)(vs - (float)ah[3]);
            vs = xb.x * LSCALE; ah[4] = (_Float16)vs; al_[4] = (_Float16)(vs - (float)ah[4]);
            vs = xb.y * LSCALE; ah[5] = (_Float16)vs; al_[5] = (_Float16)(vs - (float)ah[5]);
            vs = xb.z * LSCALE; ah[6] = (_Float16)vs; al_[6] = (_Float16)(vs - (float)ah[6]);
            vs = xb.w * LSCALE; ah[7] = (_Float16)vs; al_[7] = (_Float16)(vs - (float)ah[7]);
        }
        acc0 = __builtin_amdgcn_mfma_f32_16x16x32_f16(ah,  bh0, acc0, 0, 0, 0);
        acc0 = __builtin_amdgcn_mfma_f32_16x16x32_f16(al_, bh0, acc0, 0, 0, 0);
        acc0 = __builtin_amdgcn_mfma_f32_16x16x32_f16(ah,  bl0, acc0, 0, 0, 0);
        acc1 = __builtin_amdgcn_mfma_f32_16x16x32_f16(ah,  bh1, acc1, 0, 0, 0);
        acc1 = __builtin_amdgcn_mfma_f32_16x16x32_f16(al_, bh1, acc1, 0, 0, 0);
        acc1 = __builtin_amdgcn_mfma_f32_16x16x32_f16(ah,  bl1, acc1, 0, 0, 0);
        acc2 = __builtin_amdgcn_mfma_f32_16x16x32_f16(ah,  bh2, acc2, 0, 0, 0);
        acc2 = __builtin_amdgcn_mfma_f32_16x16x32_f16(al_, bh2, acc2, 0, 0, 0);
        acc2 = __builtin_amdgcn_mfma_f32_16x16x32_f16(ah,  bl2, acc2, 0, 0, 0);
        acc3 = __builtin_amdgcn_mfma_f32_16x16x32_f16(ah,  bh3, acc3, 0, 0, 0);
        acc3 = __builtin_amdgcn_mfma_f32_16x16x32_f16(al_, bh3, acc3, 0, 0, 0);
        acc3 = __builtin_amdgcn_mfma_f32_16x16x32_f16(ah,  bl3, acc3, 0, 0, 0);
    };

#define KSTEP(KC, CSLOT, SSLOT)                                          \
    do {                                                                 \
        asm volatile("s_waitcnt vmcnt(10)" ::: "memory");                \
        __builtin_amdgcn_sched_barrier(0);                               \
        if ((KC) + 2 < NKC) STAGE((KC) + 2, (SSLOT));                    \
        __builtin_amdgcn_sched_barrier(0);                               \
        COMPUTE(CSLOT);                                                  \
    } while (0)

    // prologue: pages 0,1 in flight (20 loads)
    STAGE(0, 0); STAGE(1, 1);
    // steady state: kc = 0..62, slots static via x3 unroll
    for (int m = 0; m < 21; ++m) {
        const int kc = m * 3;
        KSTEP(kc + 0, 0, 2);
        KSTEP(kc + 1, 1, 0);
        KSTEP(kc + 2, 2, 1);
    }
    // peeled kc = 63 (slot 0)
    asm volatile("s_waitcnt vmcnt(0)" ::: "memory");
    __builtin_amdgcn_sched_barrier(0);
    COMPUTE(0);
#undef KSTEP

    // all waves done with their rings before logits alias wave 0's region
    __syncthreads();

    // ---- C tiles -> LDS logits. C layout: col = lane&15, row = (lane>>4)*4+r;
    // token = w*16 + row.
    {
        float* logits = smem;
        const int col = l & 15;
#pragma unroll
        for (int r = 0; r < 4; ++r) {
            const int t = w * 16 + g * 4 + r;
            logits[t * 65 + 0  + col] = acc0[r] * LSCALE2_INV;
            logits[t * 65 + 16 + col] = acc1[r] * LSCALE2_INV;
            logits[t * 65 + 32 + col] = acc2[r] * LSCALE2_INV;
            logits[t * 65 + 48 + col] = acc3[r] * LSCALE2_INV;
        }
    }
    __syncthreads();

    // ---- top-2 + 2-way softmax (frozen scan): thread t handles token t ----
    float* res = smem + TPB * 65;
    if (tid < TPB) {
        const float* lg = smem + tid * 65;
        float m1 = -INFINITY, m2 = -INFINITY;
        int i1 = 0, i2 = 0;
        for (int e = 0; e < E_; ++e) {
            const float v = lg[e] + bias[e];
            if (v > m1)      { m2 = m1; i2 = i1; m1 = v; i1 = e; }
            else if (v > m2) { m2 = v;  i2 = e; }
        }
        const float ex  = expf(m2 - m1);
        const float den = 1.f + ex;
        res[tid*4+0] = 1.f / den;
        res[tid*4+1] = ex / den;
        res[tid*4+2] = (float)i1;
        res[tid*4+3] = (float)i2;
    }
    __syncthreads();

    // ---- output: probs (64 tokens x 64 experts = 4096 floats), float4 ----
    float* ob = out + (size_t)T0 * E_;
#pragma unroll
    for (int i = 0; i < 4; ++i) {
        const int idx = i * 1024 + tid * 4;
        const int t   = idx >> 6;
        const int e0  = idx & 63;
        const float p1 = res[t*4+0];
        const float p2 = res[t*4+1];
        const int   i1 = (int)res[t*4+2];
        const int   i2 = (int)res[t*4+3];
        float4 v;
        v.x = (e0+0 == i1) ? p1 : ((e0+0 == i2) ? p2 : 0.f);
        v.y = (e0+1 == i1) ? p1 : ((e0+1 == i2) ? p2 : 0.f);
        v.z = (e0+2 == i1) ? p1 : ((e0+2 == i2) ? p2 : 0.f);
        v.w = (e0+3 == i1) ? p1 : ((e0+3 == i2) ? p2 : 0.f);
        *reinterpret_cast<float4*>(ob + idx) = v;
    }
    // ids as float values (whole d_out is read as float32)
    if (tid < TPB * 2) {
        out[(size_t)NTOK * E_ + (size_t)T0 * 2 + tid] =
            res[(tid >> 1) * 4 + 2 + (tid & 1)];
    }
}

extern "C" void kernel_launch(void* const* d_in, const int* in_sizes, int n_in,
                              void* d_out, int out_size, void* d_ws, size_t ws_size,
                              hipStream_t stream) {
    const float* x = (const float*)d_in[0];
    const float* W = (const float*)d_in[1];
    const float* b = (const float*)d_in[2];
    float* out     = (float*)d_out;
    _Float16* wh   = (_Float16*)d_ws;                       // 256 KB
    _Float16* wl   = wh + (size_t)4 * NKC * 64 * 8;         // +256 KB

    hipLaunchKernelGGL(prep_w, dim3(64), dim3(256), 0, stream, W, wh, wl);
    hipLaunchKernelGGL(router_mfma, dim3(NTOK / TPB), dim3(256), 0, stream,
                       x, wh, wl, b, out);
}

// Round 19
// 49.336 us; speedup vs baseline: 1.5378x; 1.2519x over previous
//
#include <hip/hip_runtime.h>
#include <math.h>

#define NTOK 16384
#define D_   2048
#define E_   64
#define TPB  16            // tokens per block (= per wave)
#define NKC  (D_/32)       // 64 k32-steps

typedef _Float16 f16x8 __attribute__((ext_vector_type(8)));
typedef float    f32x4 __attribute__((ext_vector_type(4)));

#define LSCALE      256.0f          // pre-scale x and W before f16 split (denorm guard)
#define LSCALE2_INV (1.0f/65536.0f) // exact pow2 un-scale of acc

// ---- Kernel 1: W (E x D fp32) -> fragment-ordered f16 hi/lo, scaled x256 ----
// Fragment order: element j of lane l for (n-tile nt, k32-step kc) is
//   W[e = nt*16 + (l&15)][k = kc*32 + (l>>4)*4 + (j&3) + (j>=4 ? 16 : 0)]
// Same k-map as the A operand -> any deviation from HW k-order cancels.
__global__ __launch_bounds__(256)
void prep_w(const float* __restrict__ W,
            _Float16* __restrict__ wh, _Float16* __restrict__ wl)
{
    const int idx = blockIdx.x * 256 + threadIdx.x;   // 0..16383
    const int l  = idx & 63;
    const int kc = (idx >> 6) & 63;
    const int nt = idx >> 12;                          // 0..3
    const int e  = nt * 16 + (l & 15);
    const int g  = l >> 4;
    const float* src = W + (size_t)e * D_ + kc * 32 + g * 4;
    const float4 f0 = *reinterpret_cast<const float4*>(src);
    const float4 f1 = *reinterpret_cast<const float4*>(src + 16);
    const float v[8] = {f0.x, f0.y, f0.z, f0.w, f1.x, f1.y, f1.z, f1.w};
    f16x8 h, lo;
#pragma unroll
    for (int j = 0; j < 8; ++j) {
        const float vs = v[j] * LSCALE;
        const _Float16 hj = (_Float16)vs;
        h[j]  = hj;
        lo[j] = (_Float16)(vs - (float)hj);
    }
    *reinterpret_cast<f16x8*>(wh + (size_t)idx * 8) = h;
    *reinterpret_cast<f16x8*>(wl + (size_t)idx * 8) = lo;
}

// ---- Kernel 2: MFMA router -- r15 structure + depth-8 x ring ----
// 1024 blocks x 64 threads (1 wave = 16 tokens x all 64 experts, 4 acc tiles).
// Identical to round 15 (best: 49.5 us) except the x ring is depth-8
// (B stays depth-4): B is L2-resident (~200 cyc; 4-kc slack covers it) but
// x comes from L3/HBM (~900+ cyc; 4-kc slack ~520 cyc undershoots by ~400
// cyc/kc ~= 10 us over 64 kc). Slots stay statically indexed (rule #20) by
// pairing supersteps: even s uses x slots 0-3, odd s uses 4-7.
// sched_barrier(0) after each prefetch group (r15's proven fence).
// Per-(token,expert) chain (hh,lh,hl; nt 0..3; kc ascending; same cvt, same
// fragment maps) is bitwise-identical to rounds 5-18 (absmax 1.0; do NOT
// reorder).
__global__ __launch_bounds__(64, 1)
void router_mfma(const float* __restrict__ x,
                 const _Float16* __restrict__ wh,
                 const _Float16* __restrict__ wl,
                 const float* __restrict__ bias,
                 float* __restrict__ out)
{
    __shared__ float smem[TPB * 65 + TPB * 4];   // logits [16][65] + res [16][4]

    const int l  = threadIdx.x;                  // 0..63, one wave
    const int T0 = blockIdx.x * TPB;
    const int g  = l >> 4;

    const float* xp = x + (size_t)(T0 + (l & 15)) * D_ + g * 4;
    const _Float16* bh_b = wh + (size_t)l * 8;   // + nt*32768 + kc*512
    const _Float16* bl_b = wl + (size_t)l * 8;

    f32x4 acc0 = {0.f,0.f,0.f,0.f}, acc1 = {0.f,0.f,0.f,0.f};
    f32x4 acc2 = {0.f,0.f,0.f,0.f}, acc3 = {0.f,0.f,0.f,0.f};

    float4 xa[8], xb[8];          // x ring, slot = kc&7 (static via pairing)
    f16x8  BH[4][4], BL[4][4];    // B ring, slot = kc&3, [slot][nt]

    // one kc-step: cvt (frozen) + 12 MFMA (frozen chain) + optional prefetch
    auto STEP = [&](float4& XA, float4& XB, f16x8 (&BHj)[4], f16x8 (&BLj)[4],
                    int kc, bool pfx, bool pfb) {
        f16x8 ah, al_;
        {
            float vs;
            vs = XA.x * LSCALE; ah[0] = (_Float16)vs; al_[0] = (_Float16)(vs - (float)ah[0]);
            vs = XA.y * LSCALE; ah[1] = (_Float16)vs; al_[1] = (_Float16)(vs - (float)ah[1]);
            vs = XA.z * LSCALE; ah[2] = (_Float16)vs; al_[2] = (_Float16)(vs - (float)ah[2]);
            vs = XA.w * LSCALE; ah[3] = (_Float16)vs; al_[3] = (_Float16)(vs - (float)ah[3]);
            vs = XB.x * LSCALE; ah[4] = (_Float16)vs; al_[4] = (_Float16)(vs - (float)ah[4]);
            vs = XB.y * LSCALE; ah[5] = (_Float16)vs; al_[5] = (_Float16)(vs - (float)ah[5]);
            vs = XB.z * LSCALE; ah[6] = (_Float16)vs; al_[6] = (_Float16)(vs - (float)ah[6]);
            vs = XB.w * LSCALE; ah[7] = (_Float16)vs; al_[7] = (_Float16)(vs - (float)ah[7]);
        }
        acc0 = __builtin_amdgcn_mfma_f32_16x16x32_f16(ah,  BHj[0], acc0, 0, 0, 0);
        acc0 = __builtin_amdgcn_mfma_f32_16x16x32_f16(al_, BHj[0], acc0, 0, 0, 0);
        acc0 = __builtin_amdgcn_mfma_f32_16x16x32_f16(ah,  BLj[0], acc0, 0, 0, 0);
        acc1 = __builtin_amdgcn_mfma_f32_16x16x32_f16(ah,  BHj[1], acc1, 0, 0, 0);
        acc1 = __builtin_amdgcn_mfma_f32_16x16x32_f16(al_, BHj[1], acc1, 0, 0, 0);
        acc1 = __builtin_amdgcn_mfma_f32_16x16x32_f16(ah,  BLj[1], acc1, 0, 0, 0);
        acc2 = __builtin_amdgcn_mfma_f32_16x16x32_f16(ah,  BHj[2], acc2, 0, 0, 0);
        acc2 = __builtin_amdgcn_mfma_f32_16x16x32_f16(al_, BHj[2], acc2, 0, 0, 0);
        acc2 = __builtin_amdgcn_mfma_f32_16x16x32_f16(ah,  BLj[2], acc2, 0, 0, 0);
        acc3 = __builtin_amdgcn_mfma_f32_16x16x32_f16(ah,  BHj[3], acc3, 0, 0, 0);
        acc3 = __builtin_amdgcn_mfma_f32_16x16x32_f16(al_, BHj[3], acc3, 0, 0, 0);
        acc3 = __builtin_amdgcn_mfma_f32_16x16x32_f16(ah,  BLj[3], acc3, 0, 0, 0);
        if (pfx) {   // refill this x slot with kc+8
            XA = *reinterpret_cast<const float4*>(xp + (kc + 8) * 32);
            XB = *reinterpret_cast<const float4*>(xp + (kc + 8) * 32 + 16);
        }
        if (pfb) {   // refill this B slot with kc+4
#pragma unroll
            for (int nt = 0; nt < 4; ++nt) {
                BHj[nt] = *reinterpret_cast<const f16x8*>(bh_b + nt * 32768 + (size_t)(kc + 4) * 512);
                BLj[nt] = *reinterpret_cast<const f16x8*>(bl_b + nt * 32768 + (size_t)(kc + 4) * 512);
            }
        }
        __builtin_amdgcn_sched_barrier(0);   // PIN: prefetches may not sink
    };

    // prologue: x kc 0..7 (8 slots), B kc 0..3 (4 slots)
#pragma unroll
    for (int j = 0; j < 4; ++j) {
        xa[j]     = *reinterpret_cast<const float4*>(xp + j * 32);
        xb[j]     = *reinterpret_cast<const float4*>(xp + j * 32 + 16);
        xa[4 + j] = *reinterpret_cast<const float4*>(xp + (4 + j) * 32);
        xb[4 + j] = *reinterpret_cast<const float4*>(xp + (4 + j) * 32 + 16);
#pragma unroll
        for (int nt = 0; nt < 4; ++nt) {
            BH[j][nt] = *reinterpret_cast<const f16x8*>(bh_b + nt * 32768 + j * 512);
            BL[j][nt] = *reinterpret_cast<const f16x8*>(bl_b + nt * 32768 + j * 512);
        }
    }

    // steady state: superstep pairs m = 0..6 (s = 0..13), full prefetch.
    // max x prefetch kc+8 = (48+4+3)+8 = 63; max B prefetch at s=14: 59+4 = 63.
    for (int m = 0; m < 7; ++m) {
        const int K = m << 3;
#pragma unroll
        for (int j = 0; j < 4; ++j)      // even superstep: x slots 0-3
            STEP(xa[j], xb[j], BH[j], BL[j], K + j, true, true);
#pragma unroll
        for (int j = 0; j < 4; ++j)      // odd superstep: x slots 4-7
            STEP(xa[4 + j], xb[4 + j], BH[j], BL[j], K + 4 + j, true, true);
    }
    // s = 14 (kc 56..59): B prefetch only
#pragma unroll
    for (int j = 0; j < 4; ++j)
        STEP(xa[j], xb[j], BH[j], BL[j], 56 + j, false, true);
    // s = 15 (kc 60..63): peeled, no prefetch
#pragma unroll
    for (int j = 0; j < 4; ++j)
        STEP(xa[4 + j], xb[4 + j], BH[j], BL[j], 60 + j, false, false);

    // ---- C tiles -> LDS logits. C layout: col = lane&15, row = (lane>>4)*4+r ----
    {
        const int col = l & 15;
#pragma unroll
        for (int r = 0; r < 4; ++r) {
            const int t = g * 4 + r;
            smem[t * 65 + 0  + col] = acc0[r] * LSCALE2_INV;
            smem[t * 65 + 16 + col] = acc1[r] * LSCALE2_INV;
            smem[t * 65 + 32 + col] = acc2[r] * LSCALE2_INV;
            smem[t * 65 + 48 + col] = acc3[r] * LSCALE2_INV;
        }
    }
    __syncthreads();   // single wave: LDS drain

    // ---- top-2 + 2-way softmax (frozen scan): lane t handles token t ----
    float* res = smem + TPB * 65;
    if (l < TPB) {
        const float* lg = smem + l * 65;
        float m1 = -INFINITY, m2 = -INFINITY;
        int i1 = 0, i2 = 0;
        for (int e = 0; e < E_; ++e) {
            const float v = lg[e] + bias[e];
            if (v > m1)      { m2 = m1; i2 = i1; m1 = v; i1 = e; }
            else if (v > m2) { m2 = v;  i2 = e; }
        }
        const float ex  = expf(m2 - m1);
        const float den = 1.f + ex;
        res[l*4+0] = 1.f / den;
        res[l*4+1] = ex / den;
        res[l*4+2] = (float)i1;
        res[l*4+3] = (float)i2;
    }
    __syncthreads();

    // ---- output: probs (16 tokens x 64 experts = 1024 floats), float4 ----
    float* ob = out + (size_t)T0 * E_;
#pragma unroll
    for (int i = 0; i < 4; ++i) {
        const int idx = i * 256 + l * 4;
        const int t   = idx >> 6;
        const int e0  = idx & 63;
        const float p1 = res[t*4+0];
        const float p2 = res[t*4+1];
        const int   i1 = (int)res[t*4+2];
        const int   i2 = (int)res[t*4+3];
        float4 v;
        v.x = (e0+0 == i1) ? p1 : ((e0+0 == i2) ? p2 : 0.f);
        v.y = (e0+1 == i1) ? p1 : ((e0+1 == i2) ? p2 : 0.f);
        v.z = (e0+2 == i1) ? p1 : ((e0+2 == i2) ? p2 : 0.f);
        v.w = (e0+3 == i1) ? p1 : ((e0+3 == i2) ? p2 : 0.f);
        *reinterpret_cast<float4*>(ob + idx) = v;
    }
    // ids as float values (whole d_out is read as float32)
    if (l < TPB * 2) {
        out[(size_t)NTOK * E_ + (size_t)T0 * 2 + l] =
            res[(l >> 1) * 4 + 2 + (l & 1)];
    }
}

extern "C" void kernel_launch(void* const* d_in, const int* in_sizes, int n_in,
                              void* d_out, int out_size, void* d_ws, size_t ws_size,
                              hipStream_t stream) {
    const float* x = (const float*)d_in[0];
    const float* W = (const float*)d_in[1];
    const float* b = (const float*)d_in[2];
    float* out     = (float*)d_out;
    _Float16* wh   = (_Float16*)d_ws;                       // 256 KB
    _Float16* wl   = wh + (size_t)4 * NKC * 64 * 8;         // +256 KB

    hipLaunchKernelGGL(prep_w, dim3(64), dim3(256), 0, stream, W, wh, wl);
    hipLaunchKernelGGL(router_mfma, dim3(NTOK / TPB), dim3(64), 0, stream,
                       x, wh, wl, b, out);
}